// Round 4
// baseline (589.371 us; speedup 1.0000x reference)
//
#include <hip/hip_runtime.h>

// y[b,h,l] = sum_{m<=l} x[b,h,m] k[h,l-m] + D[h] x[b,h,l]   (C = 1)
// One block per h (1024 threads). K = FFT(k) once (spectrum held in regs,
// pre-scaled by 1/N). For batch pairs (0,1),(2,3): z = x_b0 + i x_b1,
// Y = FFT(z)*Kspec, ifft(Y) = y_b0 + i y_b1 (both real).
// Stage fusion: first fwd stage fused with load (upper half zero); last fwd
// stage + pointwise + first inverse stage done in registers on pairs
// (2t,2t+1); final inverse stage fused with epilogue (only low half needed).
#define Bdim 4
#define Hdim 1024
#define Ldim 4096
#define NFFT 8192
#define NTHR 1024
#define LOG2T 10
#define BPT  (NFFT / 2 / NTHR)   // butterflies/thread/stage = 4
#define EPT  (Ldim / NTHR)       // input elems/thread = 4

// LDS bank swizzle for float2 array: bank-pair = idx mod 16; mix bits 7:4
// into 3:0 to break stride-2/stride-4 conflict classes (8-way -> ~4-way).
__device__ __forceinline__ int SW(int i) { return i ^ ((i >> 4) & 15); }

// v_sin_f32 / v_cos_f32 take input in REVOLUTIONS (D = sin(S0*2pi)).
__device__ __forceinline__ void sincos_rev(float f, float& s, float& c) {
#if __has_builtin(__builtin_amdgcn_sinf) && __has_builtin(__builtin_amdgcn_cosf)
    s = __builtin_amdgcn_sinf(f);
    c = __builtin_amdgcn_cosf(f);
#else
    __sincosf(f * 6.28318530717958647692f, &s, &c);
#endif
}

__device__ __forceinline__ float2 cmul(float2 a, float2 b) {
    return make_float2(a.x * b.x - a.y * b.y, a.x * b.y + a.y * b.x);
}

// Forward radix-2 DIF stages m = NFFT/2 .. 4 in LDS (m=NFFT fused at load,
// m=2 done in registers by the caller). Natural -> bit-reversed.
// Twiddle W_m^j = exp(-2pi*i*j/m), j = (tid + NTHR*r) & (half-1).
__device__ __forceinline__ void dif_stages_lds(float2* A, int tid) {
    for (int m = NFFT >> 1; m >= 4; m >>= 1) {
        const int half = m >> 1;
        const float invm = 1.0f / (float)m;   // power of two: exact
        float2 w0, wstep = make_float2(1.0f, 0.0f);
        if (half >= NTHR) {
            sincos_rev(-(float)tid * invm, w0.y, w0.x);
            sincos_rev(-(float)NTHR * invm, wstep.y, wstep.x);
        } else {
            sincos_rev(-(float)(tid & (half - 1)) * invm, w0.y, w0.x);
        }
        float2 w = w0;
        const int H = half >> LOG2T;          // half/NTHR (>=1 when active)
        #pragma unroll
        for (int r = 0; r < BPT; ++r) {
            int t  = tid + r * NTHR;
            int i1 = ((t & ~(half - 1)) << 1) | (t & (half - 1));
            int i2 = i1 + half;
            float2 u = A[SW(i1)];
            float2 v = A[SW(i2)];
            A[SW(i1)] = make_float2(u.x + v.x, u.y + v.y);
            float2 d = make_float2(u.x - v.x, u.y - v.y);
            A[SW(i2)] = cmul(d, w);
            if (half >= NTHR) {               // advance/reset twiddle
                if (((r + 1) & (H - 1)) == 0) w = w0;
                else                          w = cmul(w, wstep);
            }
        }
        __syncthreads();
    }
}

// Inverse radix-2 DIT stages m = 4 .. NFFT/2 in LDS (m=2 in registers by the
// caller, m=NFFT fused with the epilogue). Bit-reversed -> natural.
// Twiddle exp(+2pi*i*j/m). Unnormalized (1/N folded into kspec).
__device__ __forceinline__ void dit_stages_lds(float2* A, int tid) {
    for (int m = 4; m <= (NFFT >> 1); m <<= 1) {
        const int half = m >> 1;
        const float invm = 1.0f / (float)m;
        float2 w0, wstep = make_float2(1.0f, 0.0f);
        if (half >= NTHR) {
            sincos_rev((float)tid * invm, w0.y, w0.x);
            sincos_rev((float)NTHR * invm, wstep.y, wstep.x);
        } else {
            sincos_rev((float)(tid & (half - 1)) * invm, w0.y, w0.x);
        }
        float2 w = w0;
        const int H = half >> LOG2T;
        #pragma unroll
        for (int r = 0; r < BPT; ++r) {
            int t  = tid + r * NTHR;
            int i1 = ((t & ~(half - 1)) << 1) | (t & (half - 1));
            int i2 = i1 + half;
            float2 v = cmul(A[SW(i2)], w);
            float2 u = A[SW(i1)];
            A[SW(i1)] = make_float2(u.x + v.x, u.y + v.y);
            A[SW(i2)] = make_float2(u.x - v.x, u.y - v.y);
            if (half >= NTHR) {
                if (((r + 1) & (H - 1)) == 0) w = w0;
                else                          w = cmul(w, wstep);
            }
        }
        __syncthreads();
    }
}

__global__ __launch_bounds__(NTHR, 1)
void fftconv_kernel(const float* __restrict__ x,
                    const float* __restrict__ kin,
                    const float* __restrict__ Din,
                    float* __restrict__ out)
{
    __shared__ float2 A[NFFT];   // 64 KiB

    const int tid = threadIdx.x;
    const int h = blockIdx.x;               // one block per h, all 4 batches

    const float* kp = kin + (size_t)h * (size_t)Ldim;   // C = 1
    const float  Dh = Din[h];
    const float  invN = 1.0f / (float)NFFT;

    // First-stage twiddles (m = NFFT): W^tid and step W^NTHR (reused; the
    // final inverse stage uses their conjugates).
    float2 wf0, wfstep;
    sincos_rev(-(float)tid * (1.0f / (float)NFFT), wf0.y, wf0.x);
    sincos_rev(-(float)NTHR * (1.0f / (float)NFFT), wfstep.y, wfstep.x);

    // ---- K: load + fused DIF stage m=NFFT (upper half of input is zero) ----
    {
        float2 w = wf0;
        #pragma unroll
        for (int r = 0; r < EPT; ++r) {
            int j = tid + r * NTHR;
            float v = kp[j];
            A[SW(j)]        = make_float2(v, 0.0f);
            A[SW(j + Ldim)] = make_float2(v * w.x, v * w.y);
            w = cmul(w, wfstep);
        }
    }
    __syncthreads();
    dif_stages_lds(A, tid);                    // ends with barrier (after m=4)

    // ---- K's last stage (m=2, twiddle-free) in registers during stash, ----
    // ---- pre-scaled by 1/N. Pair-sliced layout: kspec[2r]=K[2t], [2r+1]=K[2t+1].
    float2 kspec[2 * BPT];
    #pragma unroll
    for (int r = 0; r < BPT; ++r) {
        int t = tid + r * NTHR;
        float2 q0 = A[SW(2 * t)];
        float2 q1 = A[SW(2 * t + 1)];
        kspec[2 * r]     = make_float2((q0.x + q1.x) * invN, (q0.y + q1.y) * invN);
        kspec[2 * r + 1] = make_float2((q0.x - q1.x) * invN, (q0.y - q1.y) * invN);
    }
    __syncthreads();   // stash reads pairs; next z-store writes other threads' slots

    for (int p = 0; p < 2; ++p) {
        const float* xp0 = x + ((size_t)(2 * p)     * Hdim + h) * (size_t)Ldim;
        const float* xp1 = x + ((size_t)(2 * p + 1) * Hdim + h) * (size_t)Ldim;

        // ---- z = x_b0 + i x_b1: load + fused first DIF stage ----
        float xr0[EPT], xr1[EPT];              // keep for the skip term
        {
            float2 w = wf0;
            #pragma unroll
            for (int r = 0; r < EPT; ++r) {
                int j = tid + r * NTHR;
                float2 z = make_float2(xp0[j], xp1[j]);
                xr0[r] = z.x; xr1[r] = z.y;
                A[SW(j)]        = z;
                A[SW(j + Ldim)] = cmul(z, w);
                w = cmul(w, wfstep);
            }
        }
        __syncthreads();
        dif_stages_lds(A, tid);                // ends with barrier

        // ---- registers: fwd m=2 + pointwise*Kspec + inverse m=2 ----
        // All three act on the same pair (2t, 2t+1); both stages twiddle-free.
        #pragma unroll
        for (int r = 0; r < BPT; ++r) {
            int t = tid + r * NTHR;
            float2 p0 = A[SW(2 * t)];
            float2 p1 = A[SW(2 * t + 1)];
            float2 U = make_float2(p0.x + p1.x, p0.y + p1.y);   // Z[2t]
            float2 V = make_float2(p0.x - p1.x, p0.y - p1.y);   // Z[2t+1]
            float2 Y0 = cmul(U, kspec[2 * r]);
            float2 Y1 = cmul(V, kspec[2 * r + 1]);
            A[SW(2 * t)]     = make_float2(Y0.x + Y1.x, Y0.y + Y1.y);
            A[SW(2 * t + 1)] = make_float2(Y0.x - Y1.x, Y0.y - Y1.y);
        }
        __syncthreads();
        dit_stages_lds(A, tid);                // ends with barrier

        // ---- final inverse stage (m=NFFT) fused with epilogue: only the ----
        // ---- low half is needed: y[t] = A[t] + W^{-t} * A[t+4096].      ----
        float* op0 = out + ((size_t)(2 * p)     * Hdim + h) * (size_t)Ldim;
        float* op1 = out + ((size_t)(2 * p + 1) * Hdim + h) * (size_t)Ldim;
        {
            float2 w  = make_float2(wf0.x, -wf0.y);       // conj: exp(+2pi i tid/N)
            float2 ws = make_float2(wfstep.x, -wfstep.y); // conj step
            #pragma unroll
            for (int r = 0; r < EPT; ++r) {
                int t = tid + r * NTHR;
                float2 u = A[SW(t)];
                float2 v = cmul(A[SW(t + Ldim)], w);
                op0[t] = (u.x + v.x) + Dh * xr0[r];
                op1[t] = (u.y + v.y) + Dh * xr1[r];
                w = cmul(w, ws);
            }
        }
        // Next pair's z-store writes exactly this thread's (t, t+4096) slots
        // (same own-slot set as the epilogue reads) -> no barrier needed.
    }
}

extern "C" void kernel_launch(void* const* d_in, const int* in_sizes, int n_in,
                              void* d_out, int out_size, void* d_ws, size_t ws_size,
                              hipStream_t stream)
{
    const float* x  = (const float*)d_in[0];
    const float* k  = (const float*)d_in[1];
    const float* D  = (const float*)d_in[2];
    float* out = (float*)d_out;

    dim3 grid(Hdim);          // one block per h
    dim3 block(NTHR);
    hipLaunchKernelGGL(fftconv_kernel, grid, block, 0, stream, x, k, D, out);
}

// Round 5
// 343.814 us; speedup vs baseline: 1.7142x; 1.7142x over previous
//
#include <hip/hip_runtime.h>

// y[b,h,l] = sum_{m<=l} x[b,h,m] k[h,l-m] + D[h] x[b,h,l]   (C = 1)
// One block per h (1024 threads, 8 complex elems/thread in registers).
// 8192-pt FFT as 5 register passes (radix-8 x4 + radix-2), 4 LDS exchanges.
// K = FFT(k) once -> kspec regs (pre-scaled 1/N). Batch pairs (0,1),(2,3)
// via z = x_b0 + i x_b1; ifft(FFT(z)*K) = y_b0 + i y_b1.
// Fusions: fwd pass 1 reads global (upper half zero); mid = fwd half=1 +
// pointwise + inv halves {1,2,4} in regs; last inv stage fused with epilogue.
#define Bdim 4
#define Hdim 1024
#define Ldim 4096
#define NFFT 8192
#define NTHR 1024
#define R2C 0.70710678118654752440f

// LDS float2-index swizzle: minimal-round b64 access for all strides used.
__device__ __forceinline__ int SW(int i) { return i ^ ((i >> 4) & 15); }

// v_sin_f32 / v_cos_f32 take input in REVOLUTIONS (D = sin(S0*2pi)).
__device__ __forceinline__ void sincos_rev(float f, float& s, float& c) {
#if __has_builtin(__builtin_amdgcn_sinf) && __has_builtin(__builtin_amdgcn_cosf)
    s = __builtin_amdgcn_sinf(f);
    c = __builtin_amdgcn_cosf(f);
#else
    __sincosf(f * 6.28318530717958647692f, &s, &c);
#endif
}

__device__ __forceinline__ float2 cadd(float2 a, float2 b) { return make_float2(a.x + b.x, a.y + b.y); }
__device__ __forceinline__ float2 csub(float2 a, float2 b) { return make_float2(a.x - b.x, a.y - b.y); }
__device__ __forceinline__ float2 cmul(float2 a, float2 b) {
    return make_float2(a.x * b.x - a.y * b.y, a.x * b.y + a.y * b.x);
}
__device__ __forceinline__ float2 cmuli(float2 a)    { return make_float2(-a.y, a.x); }  // a * (+i)
__device__ __forceinline__ float2 cmulnegi(float2 a) { return make_float2(a.y, -a.x); }  // a * (-i)

// ---- forward radix-8 (DIF halves {4s,2s,s}), w = exp(-2pi i (t mod s)/(8s)) ----
__device__ __forceinline__ void fwd8_bc(float2 e[8], float2 w) {
    float2 w2  = cmul(w, w);        // W_{4s}^{qm}
    float2 w2n = cmulnegi(w2);
    {   float2 u, d;
        u = e[0]; d = csub(u, e[2]); e[0] = cadd(u, e[2]); e[2] = cmul(d, w2);
        u = e[1]; d = csub(u, e[3]); e[1] = cadd(u, e[3]); e[3] = cmul(d, w2n);
        u = e[4]; d = csub(u, e[6]); e[4] = cadd(u, e[6]); e[6] = cmul(d, w2);
        u = e[5]; d = csub(u, e[7]); e[5] = cadd(u, e[7]); e[7] = cmul(d, w2n);
    }
    float2 w4 = cmul(w2, w2);       // W_{2s}^{qm}
    {   float2 u, d;
        u = e[0]; d = csub(u, e[1]); e[0] = cadd(u, e[1]); e[1] = cmul(d, w4);
        u = e[2]; d = csub(u, e[3]); e[2] = cadd(u, e[3]); e[3] = cmul(d, w4);
        u = e[4]; d = csub(u, e[5]); e[4] = cadd(u, e[5]); e[5] = cmul(d, w4);
        u = e[6]; d = csub(u, e[7]); e[6] = cadd(u, e[7]); e[7] = cmul(d, w4);
    }
}
__device__ __forceinline__ void fwd8(float2 e[8], float2 w) {
    float2 w1  = make_float2(R2C * (w.x + w.y), R2C * (w.y - w.x)); // w*W8^1
    float2 w2t = cmulnegi(w);                                        // w*W8^2
    float2 w3  = cmulnegi(w1);                                       // w*W8^3
    {   float2 u, d;
        u = e[0]; d = csub(u, e[4]); e[0] = cadd(u, e[4]); e[4] = cmul(d, w);
        u = e[1]; d = csub(u, e[5]); e[1] = cadd(u, e[5]); e[5] = cmul(d, w1);
        u = e[2]; d = csub(u, e[6]); e[2] = cadd(u, e[6]); e[6] = cmul(d, w2t);
        u = e[3]; d = csub(u, e[7]); e[3] = cadd(u, e[7]); e[7] = cmul(d, w3);
    }
    fwd8_bc(e, w);
}
// First pass variant: inputs e[4..7] are zero (zero-padded upper half).
__device__ __forceinline__ void fwd8_zero(float2 e[8], float2 w) {
    float2 w1  = make_float2(R2C * (w.x + w.y), R2C * (w.y - w.x));
    float2 w2t = cmulnegi(w);
    float2 w3  = cmulnegi(w1);
    e[4] = cmul(e[0], w); e[5] = cmul(e[1], w1);
    e[6] = cmul(e[2], w2t); e[7] = cmul(e[3], w3);
    fwd8_bc(e, w);
}

// ---- inverse radix-8 (DIT halves {s,2s,4s}), v = exp(+2pi i (t mod s)/(8s)) ----
__device__ __forceinline__ void inv8(float2 e[8], float2 v) {
    float2 v2 = cmul(v, v);
    float2 v4 = cmul(v2, v2);
    {   float2 u, tv;
        u = e[0]; tv = cmul(e[1], v4); e[0] = cadd(u, tv); e[1] = csub(u, tv);
        u = e[2]; tv = cmul(e[3], v4); e[2] = cadd(u, tv); e[3] = csub(u, tv);
        u = e[4]; tv = cmul(e[5], v4); e[4] = cadd(u, tv); e[5] = csub(u, tv);
        u = e[6]; tv = cmul(e[7], v4); e[6] = cadd(u, tv); e[7] = csub(u, tv);
    }
    float2 v2i = cmuli(v2);
    {   float2 u, tv;
        u = e[0]; tv = cmul(e[2], v2);  e[0] = cadd(u, tv); e[2] = csub(u, tv);
        u = e[1]; tv = cmul(e[3], v2i); e[1] = cadd(u, tv); e[3] = csub(u, tv);
        u = e[4]; tv = cmul(e[6], v2);  e[4] = cadd(u, tv); e[6] = csub(u, tv);
        u = e[5]; tv = cmul(e[7], v2i); e[5] = cadd(u, tv); e[7] = csub(u, tv);
    }
    float2 q1 = make_float2(R2C * (v.x - v.y), R2C * (v.x + v.y)); // v*V8^1
    float2 q2 = cmuli(v);                                           // v*V8^2
    float2 q3 = cmuli(q1);                                          // v*V8^3
    {   float2 u, tv;
        u = e[0]; tv = cmul(e[4], v);  e[0] = cadd(u, tv); e[4] = csub(u, tv);
        u = e[1]; tv = cmul(e[5], q1); e[1] = cadd(u, tv); e[5] = csub(u, tv);
        u = e[2]; tv = cmul(e[6], q2); e[2] = cadd(u, tv); e[6] = csub(u, tv);
        u = e[3]; tv = cmul(e[7], q3); e[3] = cadd(u, tv); e[7] = csub(u, tv);
    }
}
// Specialized inv8 with v = 1 (s=1 pass: all twiddles are constants).
__device__ __forceinline__ void inv8_unit(float2 e[8]) {
    {   float2 a, b;
        a = e[0]; b = e[1]; e[0] = cadd(a, b); e[1] = csub(a, b);
        a = e[2]; b = e[3]; e[2] = cadd(a, b); e[3] = csub(a, b);
        a = e[4]; b = e[5]; e[4] = cadd(a, b); e[5] = csub(a, b);
        a = e[6]; b = e[7]; e[6] = cadd(a, b); e[7] = csub(a, b);
    }
    {   float2 u, tv;
        u = e[0]; tv = e[2];        e[0] = cadd(u, tv); e[2] = csub(u, tv);
        u = e[1]; tv = cmuli(e[3]); e[1] = cadd(u, tv); e[3] = csub(u, tv);
        u = e[4]; tv = e[6];        e[4] = cadd(u, tv); e[6] = csub(u, tv);
        u = e[5]; tv = cmuli(e[7]); e[5] = cadd(u, tv); e[7] = csub(u, tv);
    }
    {   float2 u, tv;
        u = e[0]; tv = e[4];        e[0] = cadd(u, tv); e[4] = csub(u, tv);
        u = e[1]; tv = make_float2(R2C * (e[5].x - e[5].y), R2C * (e[5].x + e[5].y));
                                    e[1] = cadd(u, tv); e[5] = csub(u, tv);
        u = e[2]; tv = cmuli(e[6]); e[2] = cadd(u, tv); e[6] = csub(u, tv);
        u = e[3]; tv = make_float2(R2C * (-e[7].x - e[7].y), R2C * (e[7].x - e[7].y));
                                    e[3] = cadd(u, tv); e[7] = csub(u, tv);
    }
}

template<int S>
__device__ __forceinline__ void pass_fwd(float2* A, int t, float2 w) {
    constexpr int L = (S == 1024) ? 10 : (S == 128) ? 7 : (S == 16) ? 4 : 1;
    const int base = ((t >> L) << (L + 3)) | (t & (S - 1));
    float2 e[8];
    #pragma unroll
    for (int j = 0; j < 8; ++j) e[j] = A[SW(base + j * S)];
    fwd8(e, w);
    #pragma unroll
    for (int j = 0; j < 8; ++j) A[SW(base + j * S)] = e[j];
}

template<int S>
__device__ __forceinline__ void pass_inv(float2* A, int t, float2 v) {
    constexpr int L = (S == 512) ? 9 : (S == 64) ? 6 : 3;
    const int base = ((t >> L) << (L + 3)) | (t & (S - 1));
    float2 e[8];
    #pragma unroll
    for (int j = 0; j < 8; ++j) e[j] = A[SW(base + j * S)];
    inv8(e, v);
    #pragma unroll
    for (int j = 0; j < 8; ++j) A[SW(base + j * S)] = e[j];
}

__global__ __launch_bounds__(NTHR)   // NO 2nd arg: it forces a 64-VGPR cap + spills
void fftconv_kernel(const float* __restrict__ x,
                    const float* __restrict__ kin,
                    const float* __restrict__ Din,
                    float* __restrict__ out)
{
    __shared__ float2 A[NFFT];   // 64 KiB

    const int t = threadIdx.x;
    const int h = blockIdx.x;

    const float* kp = kin + (size_t)h * (size_t)Ldim;   // C = 1
    const float  Dh = Din[h];
    const float  invN = 1.0f / (float)NFFT;

    // Per-pass twiddle bases. Forward pass stride s: w = exp(-2pi i (t&(s-1))/(8s)).
    float2 wF1, wF2, wF3, wF4, vI2, vI3, vI4;
    sincos_rev(-(float)t         * (1.0f / 8192.0f), wF1.y, wF1.x);  // s=1024
    sincos_rev(-(float)(t & 127) * (1.0f / 1024.0f), wF2.y, wF2.x);  // s=128
    sincos_rev(-(float)(t & 15)  * (1.0f / 128.0f),  wF3.y, wF3.x);  // s=16
    sincos_rev(-(float)(t & 1)   * (1.0f / 16.0f),   wF4.y, wF4.x);  // s=2
    sincos_rev( (float)(t & 7)   * (1.0f / 64.0f),   vI2.y, vI2.x);  // s=8
    sincos_rev( (float)(t & 63)  * (1.0f / 512.0f),  vI3.y, vI3.x);  // s=64
    sincos_rev( (float)(t & 511) * (1.0f / 4096.0f), vI4.y, vI4.x);  // s=512
    const float2 vf = make_float2(wF1.x, -wF1.y);    // exp(+2pi i t/8192), epilogue

    // ================= K: forward FFT, spectrum -> kspec regs =================
    {
        float2 e[8];
        #pragma unroll
        for (int j = 0; j < 4; ++j) e[j] = make_float2(kp[t + 1024 * j], 0.0f);
        fwd8_zero(e, wF1);
        #pragma unroll
        for (int j = 0; j < 8; ++j) A[SW(t + 1024 * j)] = e[j];
    }
    __syncthreads();
    pass_fwd<128>(A, t, wF2);  __syncthreads();
    pass_fwd<16>(A, t, wF3);   __syncthreads();
    pass_fwd<2>(A, t, wF4);    __syncthreads();
    float2 kspec[8];
    {
        float2 c[8];
        #pragma unroll
        for (int j = 0; j < 8; ++j) c[j] = A[SW(8 * t + j)];
        #pragma unroll
        for (int u2 = 0; u2 < 4; ++u2) {         // fwd half=1 (twiddle-free) + 1/N
            float2 a = c[2 * u2], b = c[2 * u2 + 1];
            kspec[2 * u2]     = make_float2((a.x + b.x) * invN, (a.y + b.y) * invN);
            kspec[2 * u2 + 1] = make_float2((a.x - b.x) * invN, (a.y - b.y) * invN);
        }
    }

    // ================= batch pairs =================
    for (int p = 0; p < 2; ++p) {
        const float* xp0 = x + ((size_t)(2 * p)     * Hdim + h) * (size_t)Ldim;
        const float* xp1 = x + ((size_t)(2 * p + 1) * Hdim + h) * (size_t)Ldim;
        float xr0[4], xr1[4];

        __syncthreads();   // prior reads of A (kspec stash / epilogue) complete
        {
            float2 e[8];
            #pragma unroll
            for (int j = 0; j < 4; ++j) {
                float a = xp0[t + 1024 * j], b = xp1[t + 1024 * j];
                xr0[j] = a; xr1[j] = b;
                e[j] = make_float2(a, b);        // z = x_b0 + i x_b1
            }
            fwd8_zero(e, wF1);
            #pragma unroll
            for (int j = 0; j < 8; ++j) A[SW(t + 1024 * j)] = e[j];
        }
        __syncthreads();
        pass_fwd<128>(A, t, wF2);  __syncthreads();
        pass_fwd<16>(A, t, wF3);   __syncthreads();
        pass_fwd<2>(A, t, wF4);    __syncthreads();
        {   // mid: fwd half=1 + pointwise*Kspec + inv halves {1,2,4}, in regs
            float2 c[8];
            #pragma unroll
            for (int j = 0; j < 8; ++j) c[j] = A[SW(8 * t + j)];
            #pragma unroll
            for (int u2 = 0; u2 < 4; ++u2) {
                float2 a = c[2 * u2], b = c[2 * u2 + 1];
                c[2 * u2] = cadd(a, b); c[2 * u2 + 1] = csub(a, b);
            }
            #pragma unroll
            for (int j = 0; j < 8; ++j) c[j] = cmul(c[j], kspec[j]);
            inv8_unit(c);
            #pragma unroll
            for (int j = 0; j < 8; ++j) A[SW(8 * t + j)] = c[j];
        }
        __syncthreads();
        pass_inv<8>(A, t, vI2);    __syncthreads();
        pass_inv<64>(A, t, vI3);   __syncthreads();
        pass_inv<512>(A, t, vI4);  __syncthreads();
        {   // epilogue: last DIT stage (half=4096), low half only, + D*x skip
            float* op0 = out + ((size_t)(2 * p)     * Hdim + h) * (size_t)Ldim;
            float* op1 = out + ((size_t)(2 * p + 1) * Hdim + h) * (size_t)Ldim;
            float2 tws[4];
            tws[0] = vf;
            tws[1] = make_float2(R2C * (vf.x - vf.y), R2C * (vf.x + vf.y)); // vf*V8
            tws[2] = cmuli(vf);
            tws[3] = cmuli(tws[1]);
            #pragma unroll
            for (int r = 0; r < 4; ++r) {
                int u = t + 1024 * r;
                float2 lo = A[SW(u)];
                float2 hi = cmul(A[SW(u + 4096)], tws[r]);
                op0[u] = (lo.x + hi.x) + Dh * xr0[r];
                op1[u] = (lo.y + hi.y) + Dh * xr1[r];
            }
        }
    }
}

extern "C" void kernel_launch(void* const* d_in, const int* in_sizes, int n_in,
                              void* d_out, int out_size, void* d_ws, size_t ws_size,
                              hipStream_t stream)
{
    const float* x  = (const float*)d_in[0];
    const float* k  = (const float*)d_in[1];
    const float* D  = (const float*)d_in[2];
    float* out = (float*)d_out;

    dim3 grid(Hdim);          // one block per h
    dim3 block(NTHR);
    hipLaunchKernelGGL(fftconv_kernel, grid, block, 0, stream, x, k, D, out);
}